// Round 8
// baseline (6944.581 us; speedup 1.0000x reference)
//
#include <hip/hip_runtime.h>

typedef unsigned short u16;
typedef unsigned int u32;

#define NN 8192
#define NE 65536
#define INV160 0.07905694150420949f   // 1/sqrt(160)

__device__ __forceinline__ float BF(u16 u){ return __uint_as_float(((u32)u)<<16); }
// dual-dtype load: f=1 -> f32, f=0 -> bf16
__device__ __forceinline__ float LD(const void* p, u32 i, int f){
  return f ? ((const float*)p)[i] : BF(((const u16*)p)[i]);
}
// dual int load: f64=1 -> int64, else int32
__device__ __forceinline__ int LDI(const void* p, u32 i, int f64){
  return f64 ? (int)((const long long*)p)[i] : ((const int*)p)[i];
}
__device__ __forceinline__ u32 okey(float f){
  u32 b = __float_as_uint(f);
  return (b & 0x80000000u) ? ~b : (b | 0x80000000u);
}
__device__ __forceinline__ float okey_inv(u32 k){
  u32 b = (k & 0x80000000u) ? (k & 0x7FFFFFFFu) : ~k;
  return __uint_as_float(b);
}

// ---------------------------------------------------------------- per-buffer dtype detect
// float buffers: low u16 of each u32 word, viewed as bf16, has exponent in
// [123,131] w.p. ~0.94 if the buffer is bf16-packed; ~0.035 if f32 (uniform
// mantissa bits). Zero/one-filled buffers are dtype-agnostic (both paths read
// the correct value). edge_index: int64 has all-zero odd words.
__global__ void k_detect(
    const void* b0, const void* b1, const void* b2, const void* b3,
    const void* b4, const void* b5, const void* b6, const void* b7,
    const void* b8, const void* b9, const void* b10, const void* b11,
    const void* b12, const void* b13, const void* b14, const void* b15,
    const void* b16, const void* b17, const void* b18, const void* b19,
    const void* b20, int* flags)
{
  const void* bufs[21] = {b0,b1,b2,b3,b4,b5,b6,b7,b8,b9,b10,
                          b11,b12,b13,b14,b15,b16,b17,b18,b19,b20};
  int i = threadIdx.x;
  if (i >= 21) return;
  const u32* w = (const u32*)bufs[i];
  if (i == 3){
    int allz = 1;
    for (int k=0;k<32;k++) if (w[2*k+1] != 0u) allz = 0;
    flags[3] = allz;             // 1 = int64
  } else {
    int cnt = 0;
    for (int k=0;k<40;k++){
      u32 lo = w[k] & 0xFFFFu;
      u32 e = (lo>>7)&0xFFu;
      if (e>=123u && e<=131u) cnt++;
    }
    flags[i] = (cnt>=20) ? 0 : 1;  // 0=bf16, 1=f32
  }
}

__global__ void k_sentinel(float* __restrict__ out, int n){
  int i = blockIdx.x*256+threadIdx.x;
  if (i<n) out[i] = 12345.0f;
}

// ---------------------------------------------------------------- q per node (honest o3-linear)
// qtab[n][1280]: [0,512) q_s (o=h*64+d); [512+o*3+c] q_v (o=h*32+d)
__global__ __launch_bounds__(256) void k_qnode(
    const void* __restrict__ X, const void* __restrict__ Wq_s,
    const void* __restrict__ Wq_v, const int* __restrict__ flags,
    float* __restrict__ qtab)
{
  __shared__ float xr[160];
  const int fX=flags[0], fqs=flags[4], fqv=flags[5];
  const int t=threadIdx.x, n=blockIdx.x;
  if (t<160) xr[t] = LD(X,(u32)n*160+t,fX);
  __syncthreads();
  float a1=0.f,a2=0.f;
  for(int i=0;i<64;i++){
    float s=xr[i];
    a1 += s*LD(Wq_s,i*512+t,fqs);
    a2 += s*LD(Wq_s,i*512+t+256,fqs);
  }
  qtab[(u32)n*1280+t]     = a1*0.125f;                  // 1/sqrt(64)
  qtab[(u32)n*1280+t+256] = a2*0.125f;
  float v0=0.f,v1=0.f,v2=0.f;
  for(int j=0;j<32;j++){
    float w=LD(Wq_v,j*256+t,fqv);
    v0+=xr[64+j*3+0]*w; v1+=xr[64+j*3+1]*w; v2+=xr[64+j*3+2]*w;
  }
  qtab[(u32)n*1280+512+t*3+0]=v0*0.17677669529663687f;  // 1/sqrt(32)
  qtab[(u32)n*1280+512+t*3+1]=v1*0.17677669529663687f;
  qtab[(u32)n*1280+512+t*3+2]=v2*0.17677669529663687f;
}

// ---------------------------------------------------------------- per-edge K + logits (honest, concat form)
// 4 edges/block. k = o3_linear(cat[x_src,x_dst], Wk); logit[h] = q[src].k / sqrt(160)
__global__ __launch_bounds__(256) void k_elog(
    const void* __restrict__ X, const void* __restrict__ ei,
    const void* __restrict__ Wk_s, const void* __restrict__ Wk_v,
    const int* __restrict__ flags, const float* __restrict__ qtab,
    float* __restrict__ logits)
{
  __shared__ float xst[8][160];
  __shared__ float lsum[4][8];
  __shared__ int sd[4][2];
  const int fX=flags[0], fks=flags[6], fkv=flags[7], f64=flags[3];
  const int t=threadIdx.x;
  const int eb=blockIdx.x*4;
  if (t<8){
    int e=eb+(t>>1);
    sd[t>>1][t&1] = LDI(ei, (t&1)? (u32)NE+e : (u32)e, f64);
  }
  if (t<32) lsum[t>>3][t&7]=0.f;
  __syncthreads();
  for(int u=t;u<1280;u+=256){
    int r=u/160, k2=u-r*160;
    xst[r][k2]=LD(X,(u32)sd[r>>1][r&1]*160+k2,fX);
  }
  __syncthreads();
  // scalar k: outputs o=t and o=t+256
  float a1[4]={0,0,0,0}, a2[4]={0,0,0,0};
  for(int i=0;i<64;i++){
    float wA1=LD(Wk_s,i*512+t,fks);
    float wA2=LD(Wk_s,i*512+t+256,fks);
    float wB1=LD(Wk_s,(64+i)*512+t,fks);
    float wB2=LD(Wk_s,(64+i)*512+t+256,fks);
    #pragma unroll
    for(int e=0;e<4;e++){
      a1[e]+=xst[e*2][i]*wA1 + xst[e*2+1][i]*wB1;
      a2[e]+=xst[e*2][i]*wA2 + xst[e*2+1][i]*wB2;
    }
  }
  // vector k: output o=t, components c
  float av[4][3]={};
  for(int j=0;j<32;j++){
    float wA=LD(Wk_v,j*256+t,fkv);
    float wB=LD(Wk_v,(32+j)*256+t,fkv);
    #pragma unroll
    for(int e=0;e<4;e++){
      #pragma unroll
      for(int c=0;c<3;c++)
        av[e][c]+=xst[e*2][64+j*3+c]*wA + xst[e*2+1][64+j*3+c]*wB;
    }
  }
  const int h1=t>>6, h2=4+(t>>6), hv=t>>5;
  #pragma unroll
  for(int e=0;e<4;e++){
    const float* q = qtab + (u32)sd[e][0]*1280;
    float c1 = a1[e]*0.08838834764831845f * q[t];        // k scale 1/sqrt(128)
    float c2 = a2[e]*0.08838834764831845f * q[t+256];
    float cv = 0.125f*(av[e][0]*q[512+t*3+0]             // k_v scale 1/sqrt(64)
                      +av[e][1]*q[512+t*3+1]
                      +av[e][2]*q[512+t*3+2]);
    atomicAdd(&lsum[e][h1],c1);
    atomicAdd(&lsum[e][h2],c2);
    atomicAdd(&lsum[e][hv],cv);
  }
  __syncthreads();
  if (t<32) logits[(u32)(eb+(t>>3))*8+(t&7)] = lsum[t>>3][t&7]*INV160;
}

// ---------------------------------------------------------------- scatter-softmax passes
__global__ __launch_bounds__(256) void k_max(
    const void* __restrict__ ei, const float* __restrict__ logits,
    const int* __restrict__ flags, u32* __restrict__ imax)
{
  int idx = blockIdx.x*256 + threadIdx.x;
  int e = idx>>3, h = idx&7;
  int dst = LDI(ei,(u32)NE+e,flags[3]);
  atomicMax(&imax[dst*8+h], okey(logits[(u32)e*8+h]));
}
__global__ __launch_bounds__(256) void k_den(
    const void* __restrict__ ei, const float* __restrict__ logits,
    const int* __restrict__ flags, const u32* __restrict__ imax,
    float* __restrict__ den)
{
  int idx = blockIdx.x*256 + threadIdx.x;
  int e = idx>>3, h = idx&7;
  int dst = LDI(ei,(u32)NE+e,flags[3]);
  float m = okey_inv(imax[dst*8+h]);
  atomicAdd(&den[dst*8+h], __expf(logits[(u32)e*8+h]-m));
}

// ---------------------------------------------------------------- per-edge sph (honest p from concat) + weighted scatter
// 8 edges/block, 32 lanes/edge; fagg[n][1280]: [h*64 + c0chan] , [512 + h*96 + j*3+c]
__global__ __launch_bounds__(256) void k_agg(
    const float* __restrict__ logits,
    const void* __restrict__ rbf, const void* __restrict__ rsh,
    const void* __restrict__ ei, const void* __restrict__ Wrbf,
    const void* __restrict__ Wp_s, const void* __restrict__ Wp_v,
    const void* __restrict__ X, const int* __restrict__ flags,
    const u32* __restrict__ imax, const float* __restrict__ den,
    float* __restrict__ fagg)
{
  __shared__ float wrb[1024];
  __shared__ float xst[16][160];
  __shared__ int sd[8][2];
  const int fX=flags[0], frb=flags[1], frs=flags[2], f64=flags[3];
  const int fps=flags[8], fpv=flags[9], fwr=flags[10];
  const int t=threadIdx.x;
  const int ebase=blockIdx.x*8;
  for(int u=t;u<1024;u+=256) wrb[u]=LD(Wrbf,u,fwr);
  if (t<16){
    int e=ebase+(t>>1);
    sd[t>>1][t&1]=LDI(ei,(t&1)?(u32)NE+e:(u32)e,f64);
  }
  __syncthreads();
  for(int u=t;u<2560;u+=256){
    int r=u/160,k2=u-r*160;
    xst[r][k2]=LD(X,(u32)sd[r>>1][r&1]*160+k2,fX);
  }
  __syncthreads();
  const int sub=t>>5, j=t&31;
  const int e=ebase+sub;
  const float* xs=xst[sub*2]; const float* xd=xst[sub*2+1];

  float ps_=0.f;
  for(int i=0;i<64;i++)
    ps_ += xs[i]*LD(Wp_s,i*32+j,fps) + xd[i]*LD(Wp_s,(64+i)*32+j,fps);
  ps_ *= 0.08838834764831845f;                         // 1/sqrt(128)
  float pv_[3]={0.f,0.f,0.f};
  for(int k2=0;k2<32;k2++){
    float w1=LD(Wp_v,k2*32+j,fpv), w2=LD(Wp_v,(32+k2)*32+j,fpv);
    #pragma unroll
    for(int c=0;c<3;c++)
      pv_[c]+=xs[64+k2*3+c]*w1 + xd[64+k2*3+c]*w2;
  }
  #pragma unroll
  for(int c=0;c<3;c++) pv_[c]*=0.125f;                 // 1/sqrt(64)

  float scs=0.f, scv=0.f;
  for(int r=0;r<16;r++){
    float rb=LD(rbf,(u32)e*16+r,frb);
    scs+=rb*wrb[r*64+j]; scv+=rb*wrb[r*64+32+j];
  }
  float ss = LD(rsh,(u32)e*128+j,frs)        * scs * ps_;
  float v0 = LD(rsh,(u32)e*128+32+j*3+0,frs) * scv * pv_[0];
  float v1 = LD(rsh,(u32)e*128+32+j*3+1,frs) * scv * pv_[1];
  float v2 = LD(rsh,(u32)e*128+32+j*3+2,frs) * scv * pv_[2];
  float c0a = ss*ss;
  float c0b = (v0*v0+v1*v1+v2*v2)*0.57735026918962576f;  // 1/sqrt(3)
  float s0=ss*v0, s1=ss*v1, s2=ss*v2;

  const int dst = sd[sub][1];
  float* fa = fagg + (u32)dst*1280;
  #pragma unroll
  for (int h=0;h<8;h++){
    float m = okey_inv(imax[dst*8+h]);
    float d = den[dst*8+h];
    float w = (d>0.f) ? __expf(logits[(u32)e*8+h]-m)/d : 0.f;
    atomicAdd(fa + h*64 + j,        w*c0a);
    atomicAdd(fa + h*64 + 32 + j,   w*c0b);
    atomicAdd(fa + 512 + h*96 + j*3+0, w*s0);
    atomicAdd(fa + 512 + h*96 + j*3+1, w*s1);
    atomicAdd(fa + 512 + h*96 + j*3+2, w*s2);
  }
}

// ---------------------------------------------------------------- per-node: UNFOLDED Wv -> Wm + NormGate + out
__global__ __launch_bounds__(256) void k_nodeval(
    const float* __restrict__ fagg,
    const void* __restrict__ Wv_s, const void* __restrict__ Wv_v,
    const void* __restrict__ Wm_s, const void* __restrict__ Wm_v,
    const void* __restrict__ ln_g, const void* __restrict__ ln_b,
    const void* __restrict__ W1, const void* __restrict__ b1,
    const void* __restrict__ W2, const void* __restrict__ b2,
    const int* __restrict__ flags, float* __restrict__ out)
{
  __shared__ float ag[1280];
  __shared__ float msgs[512];
  __shared__ float msgv[768];
  __shared__ float mrow[160];
  __shared__ float n0[96], x1[96], y1[96], fl[96];
  const int fvs=flags[11], fvv=flags[12], fms=flags[13], fmv=flags[14];
  const int fg=flags[15], fbb=flags[16], f1=flags[17], fb1=flags[18];
  const int f2=flags[19], fb2=flags[20];
  const int t=threadIdx.x; const int n=blockIdx.x;
  for(int u=t;u<1280;u+=256) ag[u]=fagg[(u32)n*1280+u];
  __syncthreads();

  // val-scalar (Wv_s): outputs o'=t, t+256 ; msg_s[o'=h*64+d] = (1/sqrt64) sum_i aggc0[h][i] Wv_s[i][o']
  {
    float a1=0.f,a2=0.f;
    int h1=t>>6, h2=(t+256)>>6;
    for(int i=0;i<64;i++){
      a1+=ag[h1*64+i]*LD(Wv_s,i*512+t,fvs);
      a2+=ag[h2*64+i]*LD(Wv_s,i*512+t+256,fvs);
    }
    msgs[t]=a1*0.125f; msgs[t+256]=a2*0.125f;
  }
  // val-vector (Wv_v, c1 = dup(sv)): idx = i2*3+c
  for(int r=0;r<3;r++){
    int idx=t+256*r; int i2=idx/3, c=idx-3*i2; int h=i2>>5;
    float a=0.f;
    for(int j2=0;j2<32;j2++)
      a+=ag[512+h*96+j2*3+c]*(LD(Wv_v,j2*256+i2,fvv)+LD(Wv_v,(32+j2)*256+i2,fvv));
    msgv[idx]=a*0.125f;                                // 1/sqrt(64)
  }
  __syncthreads();

  // m-linear (Wm)
  if (t<64){
    float a=0.f;
    for(int i=0;i<512;i++) a+=msgs[i]*LD(Wm_s,i*64+t,fms);
    mrow[t]=a*0.04419417382415922f;                    // 1/sqrt(512)
  } else if (t<160){
    int idx=t-64; int o2=idx/3, c=idx-3*o2;
    float a=0.f;
    for(int i=0;i<256;i++) a+=msgv[i*3+c]*LD(Wm_v,i*32+o2,fmv);
    mrow[64+o2*3+c]=a*0.0625f;                         // 1/sqrt(256)
  }
  __syncthreads();

  if (t<96){
    float val;
    if (t<64) val=fabsf(mrow[t]);
    else { int o2=t-64;
      float a=mrow[64+o2*3],b=mrow[64+o2*3+1],c=mrow[64+o2*3+2];
      val=sqrtf(a*a+b*b+c*c); }
    n0[t]=val;
  }
  __syncthreads();
  float mu=0.f,ss2=0.f;
  for(int i=0;i<96;i++){ float v=n0[i]; mu+=v; ss2+=v*v; }
  mu*=(1.f/96.f);
  float var=fmaxf(ss2*(1.f/96.f)-mu*mu,0.f);
  float rstd=rsqrtf(var+1e-5f);
  if (t<96) x1[t]=(n0[t]-mu)*rstd*LD(ln_g,t,fg)+LD(ln_b,t,fbb);
  __syncthreads();
  if (t<96){
    float a=LD(b1,t,fb1);
    for(int i=0;i<96;i++) a+=x1[i]*LD(W1,i*96+t,f1);
    y1[t]=a/(1.f+__expf(-a));                          // silu
  }
  __syncthreads();
  if (t<96){
    float a=LD(b2,t,fb2);
    for(int i=0;i<96;i++) a+=y1[i]*LD(W2,i*96+t,f2);
    float gg=a/(1.f+__expf(-a));
    fl[t]=gg/(n0[t]+1e-6f);
  }
  __syncthreads();
  if (t<160){
    float v;
    if (t<64) v=mrow[t]*fl[t];
    else { int q=t-64; int o2=q/3; v=mrow[t]*fl[64+o2]; }
    out[(u32)n*160+t]=v;
  }
}

// ---------------------------------------------------------------- launch
extern "C" void kernel_launch(void* const* d_in, const int* in_sizes, int n_in,
                              void* d_out, int out_size, void* d_ws, size_t ws_size,
                              hipStream_t stream)
{
  (void)in_sizes; (void)n_in;
  const void* X    = d_in[0];
  const void* rbf  = d_in[1];
  const void* rsh  = d_in[2];
  const void* ei   = d_in[3];
  const void* Wq_s = d_in[4];
  const void* Wq_v = d_in[5];
  const void* Wk_s = d_in[6];
  const void* Wk_v = d_in[7];
  const void* Wp_s = d_in[8];
  const void* Wp_v = d_in[9];
  const void* Wrbf = d_in[10];
  const void* Wv_s = d_in[11];
  const void* Wv_v = d_in[12];
  const void* Wm_s = d_in[13];
  const void* Wm_v = d_in[14];
  const void* ln_g = d_in[15];
  const void* ln_b = d_in[16];
  const void* W1   = d_in[17];
  const void* b1   = d_in[18];
  const void* W2   = d_in[19];
  const void* b2   = d_in[20];

  // ws layout (~44.5 MB)
  char* w = (char*)d_ws;
  int* flags     = (int*)w;   w += 256;
  float* logits  = (float*)w; w += (size_t)NE*8*4;
  u32* imax      = (u32*)w;   w += (size_t)NN*8*4;
  float* den     = (float*)w; w += (size_t)NN*8*4;
  char* uni = w;              w += (size_t)NN*1280*4;  // qtab then fagg (overlay)
  float* qtab = (float*)uni;
  float* fagg = (float*)uni;
  size_t required = (size_t)(w - (char*)d_ws);

  if (ws_size < required){
    k_sentinel<<<(out_size+255)/256,256,0,stream>>>((float*)d_out, out_size);
    return;
  }

  hipMemsetAsync(imax, 0, (size_t)NN*8*4, stream);
  hipMemsetAsync(den,  0, (size_t)NN*8*4, stream);
  k_detect<<<1,64,0,stream>>>(X,rbf,rsh,ei,Wq_s,Wq_v,Wk_s,Wk_v,Wp_s,Wp_v,
                              Wrbf,Wv_s,Wv_v,Wm_s,Wm_v,ln_g,ln_b,W1,b1,W2,b2,flags);
  k_qnode<<<NN,256,0,stream>>>(X,Wq_s,Wq_v,flags,qtab);
  k_elog<<<NE/4,256,0,stream>>>(X,ei,Wk_s,Wk_v,flags,qtab,logits);  // qtab dies here
  hipMemsetAsync(fagg, 0, (size_t)NN*1280*4, stream);               // fagg overlays qtab
  k_max<<<NE*8/256,256,0,stream>>>(ei,logits,flags,imax);
  k_den<<<NE*8/256,256,0,stream>>>(ei,logits,flags,imax,den);
  k_agg<<<NE/8,256,0,stream>>>(logits,rbf,rsh,ei,Wrbf,Wp_s,Wp_v,X,flags,imax,den,fagg);
  k_nodeval<<<NN,256,0,stream>>>(fagg,Wv_s,Wv_v,Wm_s,Wm_v,ln_g,ln_b,W1,b1,W2,b2,flags,(float*)d_out);
}